// Round 1
// baseline (536.072 us; speedup 1.0000x reference)
//
#include <hip/hip_runtime.h>

// ---------------------------------------------------------------------------
// Generic 3x3 conv, pad=1, stride s, optional bias/relu. One thread per output
// element. All tensors NCHW fp32.
// ---------------------------------------------------------------------------
__global__ void conv3x3_k(const float* __restrict__ in, const float* __restrict__ w,
                          const float* __restrict__ b, float* __restrict__ out,
                          int N, int Cin, int Hin, int Win,
                          int Cout, int Hout, int Wout, int stride, int do_relu)
{
    int idx = blockIdx.x * blockDim.x + threadIdx.x;
    int total = N * Cout * Hout * Wout;
    if (idx >= total) return;
    int ow = idx % Wout;
    int oh = (idx / Wout) % Hout;
    int co = (idx / (Wout * Hout)) % Cout;
    int n  = idx / (Wout * Hout * Cout);

    float acc = b ? b[co] : 0.0f;
    const float* wco = w + (size_t)co * Cin * 9;
    for (int ci = 0; ci < Cin; ++ci) {
        const float* ib = in + ((size_t)(n * Cin + ci)) * Hin * Win;
        const float* wb = wco + ci * 9;
        #pragma unroll
        for (int kh = 0; kh < 3; ++kh) {
            int ih = oh * stride - 1 + kh;
            if (ih < 0 || ih >= Hin) continue;
            const float* row = ib + (size_t)ih * Win;
            #pragma unroll
            for (int kw = 0; kw < 3; ++kw) {
                int iw = ow * stride - 1 + kw;
                if (iw < 0 || iw >= Win) continue;
                acc = fmaf(row[iw], wb[kh * 3 + kw], acc);
            }
        }
    }
    if (do_relu) acc = fmaxf(acc, 0.0f);
    out[idx] = acc;
}

// ---------------------------------------------------------------------------
// Fully connected: out[n][o] = b[o] + dot(in[n,:], w[o,:]), optional relu.
// w row-major [OUT][IN]. One thread per output element.
// ---------------------------------------------------------------------------
__global__ void fc_k(const float* __restrict__ in, const float* __restrict__ w,
                     const float* __restrict__ b, float* __restrict__ out,
                     int N, int IN, int OUT, int do_relu)
{
    int idx = blockIdx.x * blockDim.x + threadIdx.x;
    if (idx >= N * OUT) return;
    int o = idx % OUT;
    int n = idx / OUT;
    const float* ib = in + (size_t)n * IN;
    const float* wb = w + (size_t)o * IN;
    float acc = b[o];
    for (int i = 0; i < IN; ++i) acc = fmaf(ib[i], wb[i], acc);
    if (do_relu) acc = fmaxf(acc, 0.0f);
    out[idx] = acc;
}

// ---------------------------------------------------------------------------
// fusion = relu(loc + glob) ; grid = pw(1x1 conv) @ fusion + pb
// loc: [N,64,16,16], glob: [N,64], pw: [96,64], pb: [96] -> grid [N,96,16,16]
// ---------------------------------------------------------------------------
__global__ void fusion_pw_k(const float* __restrict__ loc, const float* __restrict__ glob,
                            const float* __restrict__ pw, const float* __restrict__ pb,
                            float* __restrict__ grid, int N)
{
    int idx = blockIdx.x * blockDim.x + threadIdx.x;
    int total = N * 96 * 256;
    if (idx >= total) return;
    int hw = idx % 256;
    int co = (idx / 256) % 96;
    int n  = idx / (256 * 96);
    float acc = pb[co];
    const float* lb = loc + (size_t)n * 64 * 256 + hw;
    const float* gb = glob + (size_t)n * 64;
    const float* wb = pw + (size_t)co * 64;
    #pragma unroll 8
    for (int ci = 0; ci < 64; ++ci) {
        float f = fmaxf(lb[ci * 256] + gb[ci], 0.0f);
        acc = fmaf(f, wb[ci], acc);
    }
    grid[idx] = acc;
}

// ---------------------------------------------------------------------------
// Fused guide computation + trilinear grid slice + affine apply.
// fullres: [N,3,H,W]; grid: [N,96,16,16] viewed as [N,12,8,16,16];
// out: [N,3,H,W]. One thread per pixel.
// ---------------------------------------------------------------------------
__global__ void guide_slice_apply_k(const float* __restrict__ fullres,
                                    const float* __restrict__ grid,
                                    const float* __restrict__ M,
                                    const float* __restrict__ Mb,
                                    const float* __restrict__ thr,
                                    const float* __restrict__ slopes,
                                    const float* __restrict__ gbias,
                                    float* __restrict__ out,
                                    int N, int H, int W)
{
    int idx = blockIdx.x * blockDim.x + threadIdx.x;
    int total = N * H * W;
    if (idx >= total) return;
    int w = idx % W;
    int h = (idx / W) % H;
    int n = idx / (W * H);

    size_t plane = (size_t)H * W;
    size_t base  = (size_t)n * 3 * plane + (size_t)h * W + w;
    float r  = fullres[base];
    float g  = fullres[base + plane];
    float bc = fullres[base + 2 * plane];

    // ---- guide ----
    float gs = 0.0f;
    #pragma unroll
    for (int j = 0; j < 3; ++j) {
        float gj = Mb[j] + r * M[j] + g * M[3 + j] + bc * M[6 + j];
        float s = 0.0f;
        #pragma unroll
        for (int k = 0; k < 16; ++k)
            s = fmaf(slopes[j * 16 + k], fmaxf(gj - thr[j * 16 + k], 0.0f), s);
        gs += s;
    }
    float guide = fminf(fmaxf(gs * (1.0f / 3.0f) + gbias[0], 0.0f), 1.0f);

    // ---- slice coordinates (align_corners=False, border clamp) ----
    float ix = fminf(fmaxf((float)w * (16.0f / (W - 1)) - 0.5f, 0.0f), 15.0f);
    float iy = fminf(fmaxf((float)h * (16.0f / (H - 1)) - 0.5f, 0.0f), 15.0f);
    float iz = fminf(fmaxf(8.0f * guide - 0.5f, 0.0f), 7.0f);

    float x0f = floorf(ix), y0f = floorf(iy), z0f = floorf(iz);
    float wx = ix - x0f, wy = iy - y0f, wz = iz - z0f;
    int x0 = (int)x0f; int x1 = min(x0 + 1, 15);
    int y0 = (int)y0f; int y1 = min(y0 + 1, 15);
    int z0 = (int)z0f; int z1 = min(z0 + 1, 7);

    float w000 = (1.f - wz) * (1.f - wy) * (1.f - wx);
    float w001 = (1.f - wz) * (1.f - wy) * wx;
    float w010 = (1.f - wz) * wy * (1.f - wx);
    float w011 = (1.f - wz) * wy * wx;
    float w100 = wz * (1.f - wy) * (1.f - wx);
    float w101 = wz * (1.f - wy) * wx;
    float w110 = wz * wy * (1.f - wx);
    float w111 = wz * wy * wx;

    int o00 = y0 * 16 + x0, o01 = y0 * 16 + x1;
    int o10 = y1 * 16 + x0, o11 = y1 * 16 + x1;
    int z0o = z0 * 256, z1o = z1 * 256;

    const float* gn = grid + (size_t)n * 96 * 256;
    float sl[12];
    #pragma unroll
    for (int c = 0; c < 12; ++c) {
        const float* gc = gn + c * 2048;  // [8][16][16] for this coeff channel
        float v;
        v  = w000 * gc[z0o + o00];
        v  = fmaf(w001, gc[z0o + o01], v);
        v  = fmaf(w010, gc[z0o + o10], v);
        v  = fmaf(w011, gc[z0o + o11], v);
        v  = fmaf(w100, gc[z1o + o00], v);
        v  = fmaf(w101, gc[z1o + o01], v);
        v  = fmaf(w110, gc[z1o + o10], v);
        v  = fmaf(w111, gc[z1o + o11], v);
        sl[c] = v;
    }

    float rr = fmaf(r, sl[0], fmaf(g, sl[1], fmaf(bc, sl[2],  sl[3])));
    float gg = fmaf(r, sl[4], fmaf(g, sl[5], fmaf(bc, sl[6],  sl[7])));
    float bb = fmaf(r, sl[8], fmaf(g, sl[9], fmaf(bc, sl[10], sl[11])));

    size_t ob = (size_t)n * 3 * plane + (size_t)h * W + w;
    out[ob]             = rr;
    out[ob + plane]     = gg;
    out[ob + 2 * plane] = bb;
}

// ---------------------------------------------------------------------------
extern "C" void kernel_launch(void* const* d_in, const int* in_sizes, int n_in,
                              void* d_out, int out_size, void* d_ws, size_t ws_size,
                              hipStream_t stream)
{
    const float* lowres  = (const float*)d_in[0];
    const float* fullres = (const float*)d_in[1];
    const float* sw1 = (const float*)d_in[2];  const float* sb1 = (const float*)d_in[3];
    const float* sw2 = (const float*)d_in[4];  const float* sb2 = (const float*)d_in[5];
    const float* sw3 = (const float*)d_in[6];  const float* sb3 = (const float*)d_in[7];
    const float* sw4 = (const float*)d_in[8];  const float* sb4 = (const float*)d_in[9];
    const float* gw1 = (const float*)d_in[10]; const float* gb1 = (const float*)d_in[11];
    const float* gw2 = (const float*)d_in[12]; const float* gb2 = (const float*)d_in[13];
    const float* fw3 = (const float*)d_in[14]; const float* fb3 = (const float*)d_in[15];
    const float* fw4 = (const float*)d_in[16]; const float* fb4 = (const float*)d_in[17];
    const float* fw5 = (const float*)d_in[18]; const float* fb5 = (const float*)d_in[19];
    const float* lw1 = (const float*)d_in[20]; const float* lb1 = (const float*)d_in[21];
    const float* lw2 = (const float*)d_in[22];
    const float* pw  = (const float*)d_in[23]; const float* pb  = (const float*)d_in[24];
    const float* M   = (const float*)d_in[25]; const float* Mb  = (const float*)d_in[26];
    const float* thr = (const float*)d_in[27]; const float* slp = (const float*)d_in[28];
    const float* gbias = (const float*)d_in[29];

    const int N = 2, H = 1024, W = 1024;

    float* ws   = (float*)d_ws;
    float* x1   = ws;            // 2*8*128*128   = 262144
    float* x2   = x1 + 262144;   // 2*16*64*64    = 131072
    float* x3   = x2 + 131072;   // 2*32*32*32    = 65536
    float* splat= x3 + 65536;    // 2*64*16*16    = 32768
    float* g1o  = splat + 32768; // 2*64*8*8      = 8192
    float* g2o  = g1o + 8192;    // 2*64*4*4      = 2048
    float* fc3o = g2o + 2048;    // 2*256         = 512
    float* fc4o = fc3o + 512;    // 2*128         = 256
    float* glob = fc4o + 256;    // 2*64          = 128
    float* l1o  = glob + 128;    // 2*64*16*16    = 32768
    float* loc  = l1o + 32768;   // 2*64*16*16    = 32768
    float* grid = loc + 32768;   // 2*96*16*16    = 49152

    const int B = 256;
    auto blk = [](int total, int b) { return (total + b - 1) / b; };

    // low-res coefficient CNN
    conv3x3_k<<<blk(N*8*128*128, B), B, 0, stream>>>(lowres, sw1, sb1, x1,
        N, 3, 256, 256, 8, 128, 128, 2, 1);
    conv3x3_k<<<blk(N*16*64*64, B), B, 0, stream>>>(x1, sw2, sb2, x2,
        N, 8, 128, 128, 16, 64, 64, 2, 1);
    conv3x3_k<<<blk(N*32*32*32, B), B, 0, stream>>>(x2, sw3, sb3, x3,
        N, 16, 64, 64, 32, 32, 32, 2, 1);
    conv3x3_k<<<blk(N*64*16*16, B), B, 0, stream>>>(x3, sw4, sb4, splat,
        N, 32, 32, 32, 64, 16, 16, 2, 1);
    conv3x3_k<<<blk(N*64*8*8, B), B, 0, stream>>>(splat, gw1, gb1, g1o,
        N, 64, 16, 16, 64, 8, 8, 2, 1);
    conv3x3_k<<<blk(N*64*4*4, B), B, 0, stream>>>(g1o, gw2, gb2, g2o,
        N, 64, 8, 8, 64, 4, 4, 2, 1);

    // global FC path
    fc_k<<<blk(N*256, 128), 128, 0, stream>>>(g2o, fw3, fb3, fc3o, N, 1024, 256, 1);
    fc_k<<<blk(N*128, 128), 128, 0, stream>>>(fc3o, fw4, fb4, fc4o, N, 256, 128, 1);
    fc_k<<<blk(N*64, 128), 128, 0, stream>>>(fc4o, fw5, fb5, glob, N, 128, 64, 0);

    // local path
    conv3x3_k<<<blk(N*64*16*16, B), B, 0, stream>>>(splat, lw1, lb1, l1o,
        N, 64, 16, 16, 64, 16, 16, 1, 1);
    conv3x3_k<<<blk(N*64*16*16, B), B, 0, stream>>>(l1o, lw2, nullptr, loc,
        N, 64, 16, 16, 64, 16, 16, 1, 0);

    // fusion + pointwise -> bilateral grid
    fusion_pw_k<<<blk(N*96*256, B), B, 0, stream>>>(loc, glob, pw, pb, grid, N);

    // full-res guide + slice + apply
    guide_slice_apply_k<<<blk(N*H*W, B), B, 0, stream>>>(fullres, grid, M, Mb,
        thr, slp, gbias, (float*)d_out, N, H, W);
}

// Round 2
// 243.607 us; speedup vs baseline: 2.2006x; 2.2006x over previous
//
#include <hip/hip_runtime.h>

// ---------------------------------------------------------------------------
// Generic 3x3 conv, pad=1, stride s, thread-per-output (for small Cin).
// ---------------------------------------------------------------------------
__global__ void conv3x3_k(const float* __restrict__ in, const float* __restrict__ w,
                          const float* __restrict__ b, float* __restrict__ out,
                          int N, int Cin, int Hin, int Win,
                          int Cout, int Hout, int Wout, int stride, int do_relu)
{
    int idx = blockIdx.x * blockDim.x + threadIdx.x;
    int total = N * Cout * Hout * Wout;
    if (idx >= total) return;
    int ow = idx % Wout;
    int oh = (idx / Wout) % Hout;
    int co = (idx / (Wout * Hout)) % Cout;
    int n  = idx / (Wout * Hout * Cout);

    float acc = b ? b[co] : 0.0f;
    const float* wco = w + (size_t)co * Cin * 9;
    for (int ci = 0; ci < Cin; ++ci) {
        const float* ib = in + ((size_t)(n * Cin + ci)) * Hin * Win;
        const float* wb = wco + ci * 9;
        #pragma unroll
        for (int kh = 0; kh < 3; ++kh) {
            int ih = oh * stride - 1 + kh;
            if (ih < 0 || ih >= Hin) continue;
            const float* row = ib + (size_t)ih * Win;
            #pragma unroll
            for (int kw = 0; kw < 3; ++kw) {
                int iw = ow * stride - 1 + kw;
                if (iw < 0 || iw >= Win) continue;
                acc = fmaf(row[iw], wb[kh * 3 + kw], acc);
            }
        }
    }
    if (do_relu) acc = fmaxf(acc, 0.0f);
    out[idx] = acc;
}

// ---------------------------------------------------------------------------
// Wave-parallel 3x3 conv for Cin in {8,16,32,64}: each 64/CIN-lane subgroup
// computes one output element; lane handles one input channel (9 FMAs),
// then subgroup shuffle-reduce. Massively more parallelism + fewer serial
// loads per thread than thread-per-output.
// ---------------------------------------------------------------------------
template <int CIN>
__global__ void conv3x3_wave_k(const float* __restrict__ in, const float* __restrict__ w,
                               const float* __restrict__ b, float* __restrict__ out,
                               int N, int Hin, int Win,
                               int Cout, int Hout, int Wout, int stride, int do_relu)
{
    constexpr int OPW = 64 / CIN;          // outputs per wave
    int lane = threadIdx.x & 63;
    int wid  = (blockIdx.x * blockDim.x + threadIdx.x) >> 6;
    int sub  = lane / CIN;                 // which output within the wave
    int cl   = lane % CIN;                 // my input channel
    int oidx = wid * OPW + sub;
    int total = N * Cout * Hout * Wout;

    float acc = 0.0f;
    int ow = 0, oh = 0, co = 0, n = 0;
    if (oidx < total) {
        ow = oidx % Wout;
        oh = (oidx / Wout) % Hout;
        co = (oidx / (Wout * Hout)) % Cout;
        n  = oidx / (Wout * Hout * Cout);
        const float* ib = in + ((size_t)(n * CIN + cl)) * Hin * Win;
        const float* wb = w + ((size_t)co * CIN + cl) * 9;
        #pragma unroll
        for (int kh = 0; kh < 3; ++kh) {
            int ih = oh * stride - 1 + kh;
            if (ih < 0 || ih >= Hin) continue;
            const float* row = ib + (size_t)ih * Win;
            #pragma unroll
            for (int kw = 0; kw < 3; ++kw) {
                int iw = ow * stride - 1 + kw;
                if (iw < 0 || iw >= Win) continue;
                acc = fmaf(row[iw], wb[kh * 3 + kw], acc);
            }
        }
    }
    // subgroup reduce over CIN lanes (subgroups are lane-aligned)
    #pragma unroll
    for (int off = CIN / 2; off >= 1; off >>= 1)
        acc += __shfl_xor(acc, off, 64);

    if (oidx < total && cl == 0) {
        if (b) acc += b[co];
        if (do_relu) acc = fmaxf(acc, 0.0f);
        out[oidx] = acc;
    }
}

// ---------------------------------------------------------------------------
// Wave-parallel FC: one wave per output element; lanes stride over IN.
// ---------------------------------------------------------------------------
__global__ void fc_wave_k(const float* __restrict__ in, const float* __restrict__ w,
                          const float* __restrict__ b, float* __restrict__ out,
                          int N, int IN, int OUT, int do_relu)
{
    int lane = threadIdx.x & 63;
    int wid  = (blockIdx.x * blockDim.x + threadIdx.x) >> 6;
    if (wid >= N * OUT) return;
    int o = wid % OUT;
    int n = wid / OUT;
    const float* ib = in + (size_t)n * IN;
    const float* wb = w + (size_t)o * IN;
    float acc = 0.0f;
    for (int i = lane; i < IN; i += 64)
        acc = fmaf(ib[i], wb[i], acc);
    #pragma unroll
    for (int off = 32; off >= 1; off >>= 1)
        acc += __shfl_xor(acc, off, 64);
    if (lane == 0) {
        acc += b[o];
        if (do_relu) acc = fmaxf(acc, 0.0f);
        out[wid] = acc;
    }
}

// ---------------------------------------------------------------------------
// fusion = relu(loc + glob) ; grid = pw(1x1 conv) @ fusion + pb
// ---------------------------------------------------------------------------
__global__ void fusion_pw_k(const float* __restrict__ loc, const float* __restrict__ glob,
                            const float* __restrict__ pw, const float* __restrict__ pb,
                            float* __restrict__ grid, int N)
{
    int idx = blockIdx.x * blockDim.x + threadIdx.x;
    int total = N * 96 * 256;
    if (idx >= total) return;
    int hw = idx % 256;
    int co = (idx / 256) % 96;
    int n  = idx / (256 * 96);
    float acc = pb[co];
    const float* lb = loc + (size_t)n * 64 * 256 + hw;
    const float* gb = glob + (size_t)n * 64;
    const float* wb = pw + (size_t)co * 64;
    #pragma unroll 8
    for (int ci = 0; ci < 64; ++ci) {
        float f = fmaxf(lb[ci * 256] + gb[ci], 0.0f);
        acc = fmaf(f, wb[ci], acc);
    }
    grid[idx] = acc;
}

// ---------------------------------------------------------------------------
// Fused guide + trilinear slice + affine apply. One thread per pixel.
// ---------------------------------------------------------------------------
__global__ void guide_slice_apply_k(const float* __restrict__ fullres,
                                    const float* __restrict__ grid,
                                    const float* __restrict__ M,
                                    const float* __restrict__ Mb,
                                    const float* __restrict__ thr,
                                    const float* __restrict__ slopes,
                                    const float* __restrict__ gbias,
                                    float* __restrict__ out,
                                    int N, int H, int W)
{
    int idx = blockIdx.x * blockDim.x + threadIdx.x;
    int total = N * H * W;
    if (idx >= total) return;
    int w = idx % W;
    int h = (idx / W) % H;
    int n = idx / (W * H);

    size_t plane = (size_t)H * W;
    size_t base  = (size_t)n * 3 * plane + (size_t)h * W + w;
    float r  = fullres[base];
    float g  = fullres[base + plane];
    float bc = fullres[base + 2 * plane];

    float gs = 0.0f;
    #pragma unroll
    for (int j = 0; j < 3; ++j) {
        float gj = Mb[j] + r * M[j] + g * M[3 + j] + bc * M[6 + j];
        float s = 0.0f;
        #pragma unroll
        for (int k = 0; k < 16; ++k)
            s = fmaf(slopes[j * 16 + k], fmaxf(gj - thr[j * 16 + k], 0.0f), s);
        gs += s;
    }
    float guide = fminf(fmaxf(gs * (1.0f / 3.0f) + gbias[0], 0.0f), 1.0f);

    float ix = fminf(fmaxf((float)w * (16.0f / (W - 1)) - 0.5f, 0.0f), 15.0f);
    float iy = fminf(fmaxf((float)h * (16.0f / (H - 1)) - 0.5f, 0.0f), 15.0f);
    float iz = fminf(fmaxf(8.0f * guide - 0.5f, 0.0f), 7.0f);

    float x0f = floorf(ix), y0f = floorf(iy), z0f = floorf(iz);
    float wx = ix - x0f, wy = iy - y0f, wz = iz - z0f;
    int x0 = (int)x0f; int x1 = min(x0 + 1, 15);
    int y0 = (int)y0f; int y1 = min(y0 + 1, 15);
    int z0 = (int)z0f; int z1 = min(z0 + 1, 7);

    float w000 = (1.f - wz) * (1.f - wy) * (1.f - wx);
    float w001 = (1.f - wz) * (1.f - wy) * wx;
    float w010 = (1.f - wz) * wy * (1.f - wx);
    float w011 = (1.f - wz) * wy * wx;
    float w100 = wz * (1.f - wy) * (1.f - wx);
    float w101 = wz * (1.f - wy) * wx;
    float w110 = wz * wy * (1.f - wx);
    float w111 = wz * wy * wx;

    int o00 = y0 * 16 + x0, o01 = y0 * 16 + x1;
    int o10 = y1 * 16 + x0, o11 = y1 * 16 + x1;
    int z0o = z0 * 256, z1o = z1 * 256;

    const float* gn = grid + (size_t)n * 96 * 256;
    float sl[12];
    #pragma unroll
    for (int c = 0; c < 12; ++c) {
        const float* gc = gn + c * 2048;
        float v;
        v  = w000 * gc[z0o + o00];
        v  = fmaf(w001, gc[z0o + o01], v);
        v  = fmaf(w010, gc[z0o + o10], v);
        v  = fmaf(w011, gc[z0o + o11], v);
        v  = fmaf(w100, gc[z1o + o00], v);
        v  = fmaf(w101, gc[z1o + o01], v);
        v  = fmaf(w110, gc[z1o + o10], v);
        v  = fmaf(w111, gc[z1o + o11], v);
        sl[c] = v;
    }

    float rr = fmaf(r, sl[0], fmaf(g, sl[1], fmaf(bc, sl[2],  sl[3])));
    float gg = fmaf(r, sl[4], fmaf(g, sl[5], fmaf(bc, sl[6],  sl[7])));
    float bb = fmaf(r, sl[8], fmaf(g, sl[9], fmaf(bc, sl[10], sl[11])));

    size_t ob = (size_t)n * 3 * plane + (size_t)h * W + w;
    out[ob]             = rr;
    out[ob + plane]     = gg;
    out[ob + 2 * plane] = bb;
}

// ---------------------------------------------------------------------------
extern "C" void kernel_launch(void* const* d_in, const int* in_sizes, int n_in,
                              void* d_out, int out_size, void* d_ws, size_t ws_size,
                              hipStream_t stream)
{
    const float* lowres  = (const float*)d_in[0];
    const float* fullres = (const float*)d_in[1];
    const float* sw1 = (const float*)d_in[2];  const float* sb1 = (const float*)d_in[3];
    const float* sw2 = (const float*)d_in[4];  const float* sb2 = (const float*)d_in[5];
    const float* sw3 = (const float*)d_in[6];  const float* sb3 = (const float*)d_in[7];
    const float* sw4 = (const float*)d_in[8];  const float* sb4 = (const float*)d_in[9];
    const float* gw1 = (const float*)d_in[10]; const float* gb1 = (const float*)d_in[11];
    const float* gw2 = (const float*)d_in[12]; const float* gb2 = (const float*)d_in[13];
    const float* fw3 = (const float*)d_in[14]; const float* fb3 = (const float*)d_in[15];
    const float* fw4 = (const float*)d_in[16]; const float* fb4 = (const float*)d_in[17];
    const float* fw5 = (const float*)d_in[18]; const float* fb5 = (const float*)d_in[19];
    const float* lw1 = (const float*)d_in[20]; const float* lb1 = (const float*)d_in[21];
    const float* lw2 = (const float*)d_in[22];
    const float* pw  = (const float*)d_in[23]; const float* pb  = (const float*)d_in[24];
    const float* M   = (const float*)d_in[25]; const float* Mb  = (const float*)d_in[26];
    const float* thr = (const float*)d_in[27]; const float* slp = (const float*)d_in[28];
    const float* gbias = (const float*)d_in[29];

    const int N = 2, H = 1024, W = 1024;

    float* ws   = (float*)d_ws;
    float* x1   = ws;            // 2*8*128*128
    float* x2   = x1 + 262144;
    float* x3   = x2 + 131072;
    float* splat= x3 + 65536;
    float* g1o  = splat + 32768;
    float* g2o  = g1o + 8192;
    float* fc3o = g2o + 2048;
    float* fc4o = fc3o + 512;
    float* glob = fc4o + 256;
    float* l1o  = glob + 128;
    float* loc  = l1o + 32768;
    float* grid = loc + 32768;

    const int B = 256;
    auto blk = [](int total, int b) { return (total + b - 1) / b; };
    // blocks for a wave-conv: total outputs, outputs-per-wave
    auto wblk = [](int total_out, int opw) {
        int waves = (total_out + opw - 1) / opw;
        return (waves * 64 + 255) / 256;
    };

    // low-res coefficient CNN
    conv3x3_k<<<blk(N*8*128*128, B), B, 0, stream>>>(lowres, sw1, sb1, x1,
        N, 3, 256, 256, 8, 128, 128, 2, 1);
    conv3x3_wave_k<8><<<wblk(N*16*64*64, 8), B, 0, stream>>>(x1, sw2, sb2, x2,
        N, 128, 128, 16, 64, 64, 2, 1);
    conv3x3_wave_k<16><<<wblk(N*32*32*32, 4), B, 0, stream>>>(x2, sw3, sb3, x3,
        N, 64, 64, 32, 32, 32, 2, 1);
    conv3x3_wave_k<32><<<wblk(N*64*16*16, 2), B, 0, stream>>>(x3, sw4, sb4, splat,
        N, 32, 32, 64, 16, 16, 2, 1);
    conv3x3_wave_k<64><<<wblk(N*64*8*8, 1), B, 0, stream>>>(splat, gw1, gb1, g1o,
        N, 16, 16, 64, 8, 8, 2, 1);
    conv3x3_wave_k<64><<<wblk(N*64*4*4, 1), B, 0, stream>>>(g1o, gw2, gb2, g2o,
        N, 8, 8, 64, 4, 4, 2, 1);

    // global FC path (wave-parallel)
    fc_wave_k<<<wblk(N*256, 1), B, 0, stream>>>(g2o, fw3, fb3, fc3o, N, 1024, 256, 1);
    fc_wave_k<<<wblk(N*128, 1), B, 0, stream>>>(fc3o, fw4, fb4, fc4o, N, 256, 128, 1);
    fc_wave_k<<<wblk(N*64, 1), B, 0, stream>>>(fc4o, fw5, fb5, glob, N, 128, 64, 0);

    // local path
    conv3x3_wave_k<64><<<wblk(N*64*16*16, 1), B, 0, stream>>>(splat, lw1, lb1, l1o,
        N, 16, 16, 64, 16, 16, 1, 1);
    conv3x3_wave_k<64><<<wblk(N*64*16*16, 1), B, 0, stream>>>(l1o, lw2, nullptr, loc,
        N, 16, 16, 64, 16, 16, 1, 0);

    // fusion + pointwise -> bilateral grid
    fusion_pw_k<<<blk(N*96*256, B), B, 0, stream>>>(loc, glob, pw, pb, grid, N);

    // full-res guide + slice + apply
    guide_slice_apply_k<<<blk(N*H*W, B), B, 0, stream>>>(fullres, grid, M, Mb,
        thr, slp, gbias, (float*)d_out, N, H, W);
}